// Round 3
// baseline (4236.349 us; speedup 1.0000x reference)
//
#include <hip/hip_runtime.h>

typedef _Float16 f16;
typedef _Float16 half8 __attribute__((ext_vector_type(8)));
typedef float f32x4 __attribute__((ext_vector_type(4)));

#define SEQ 512
#define NB 128
#define NH 768
#define NFEAT 128
#define NGRP 8
#define BG 16
#define NCOL 48
#define NWG (NGRP*NCOL)
#define KW 192
#define NKT 6
#define PSTRIDE 98

// workspace layout (identical footprint to R2)
#define OFF_WIH   0LL
#define OFF_WHH   3538944LL
#define OFF_WLIN  7077888LL
#define OFF_XBUF  7274496LL
#define OFF_HBUF  7471104LL
#define OFF_FLG   7667712LL   /* 8 groups * 48 WGs * 4B = 1536 B (16 KB reserved) */
#define OFF_Y     7684096LL
#define OFF_TN    108347392LL
#define WS_NEED   (OFF_TN + 1024)

__global__ void fill_sentinel(float* out, long long n) {
  long long i = (long long)blockIdx.x * blockDim.x + threadIdx.x;
  long long stride = (long long)gridDim.x * blockDim.x;
  for (; i < n; i += stride) out[i] = -2.0f;
}

__global__ void prep_kernel(const float* __restrict__ Ho, const float* __restrict__ Hn,
                            const unsigned int* __restrict__ Traw,
                            const float* __restrict__ Wih, const float* __restrict__ Whh,
                            const float* __restrict__ Wlin,
                            f16* __restrict__ wih16, f16* __restrict__ whh16,
                            f16* __restrict__ wlin16,
                            f16* __restrict__ xbuf, f16* __restrict__ hbuf,
                            int* __restrict__ Tn)
{
  long long idx = (long long)blockIdx.x * blockDim.x + threadIdx.x;
  long long stride = (long long)gridDim.x * blockDim.x;
  for (long long i = idx; i < 2304LL * 768LL; i += stride) {
    wih16[i] = (f16)Wih[i];
    whh16[i] = (f16)Whh[i];
  }
  for (long long i = idx; i < 128LL * 768LL; i += stride) {
    long long b = i / 768, h = i % 768;
    wlin16[i] = (f16)Wlin[i];
    xbuf[i] = (f16)Ho[(b * 32 + 31) * 768 + h];   // H_o[:, -1, :]
    hbuf[i] = (f16)Hn[i];                          // H_n[0]
  }
  // Normalize T: detect int64 (all odd 32-bit words zero) vs int32.
  if (blockIdx.x == 0 && threadIdx.x < 128) {
    bool allz = true;
    for (int i = 0; i < 64; ++i) allz = allz && (Traw[2 * i + 1] == 0u);
    int t = threadIdx.x;
    Tn[t] = allz ? (int)Traw[2 * t] : (int)Traw[t];
  }
}

__global__ void __launch_bounds__(256, 2)
gru_kernel(const f16* __restrict__ wih16, const f16* __restrict__ whh16,
           const f16* __restrict__ xbuf, const f16* __restrict__ hbuf,
           const float* __restrict__ Hn,
           const float* __restrict__ b_ih, const float* __restrict__ b_hh,
           f16* __restrict__ Y, unsigned int* __restrict__ flag)
{
  const int wg  = blockIdx.x;
  const int g   = wg & (NGRP - 1);   // batch group (== XCD under %8 round-robin)
  const int c   = wg >> 3;           // column slice 0..47
  const int tid = threadIdx.x;
  const int lane = tid & 63;
  const int wv  = tid >> 6;          // wave 0..3 (K-split)
  const int j0  = c * 16;
  const int ks  = wv * KW;
  const int bbase = g * BG;

  __shared__ float part[4 * 16 * PSTRIDE];

  const int n15 = lane & 15;
  const int kg8 = (lane >> 4) * 8;

  // ---- persistent weight fragments (registers/AGPRs), loaded once ----
  half8 Bf[6][6];
#pragma unroll
  for (int nt = 0; nt < 6; ++nt) {
    const f16* Wsrc = (nt < 3) ? wih16 : whh16;
    const f16* base = Wsrc + (size_t)((nt % 3) * 768 + j0 + n15) * NH + ks + kg8;
#pragma unroll
    for (int kt = 0; kt < NKT; ++kt)
      Bf[nt][kt] = *(const half8*)(base + kt * 32);
  }

  // gate-phase assignment: one (batch, col) per thread; h carried in fp32 register
  const int gb = tid >> 4;
  const int gj = tid & 15;
  const int jglob = j0 + gj;
  float hcarry = Hn[(size_t)(bbase + gb) * NH + jglob];
  const float bi_r = b_ih[jglob], bi_z = b_ih[768 + jglob], bi_n = b_ih[1536 + jglob];
  const float bh_r = b_hh[jglob], bh_z = b_hh[768 + jglob], bh_n = b_hh[1536 + jglob];

  const size_t arow_off = (size_t)(bbase + n15) * NH + ks + kg8;
  const size_t ywr_off  = (size_t)(bbase + gb) * NH + jglob;

  // wave wv's k-slice [192*wv, 192*wv+192) is produced by WGs c in [12*wv, 12*wv+12)
  unsigned int* fg = flag + g * NCOL;
  const int pidx = wv * 12 + (lane < 12 ? lane : 0);

  for (int s = 0; s < SEQ; ++s) {
    // ---- wait for this wave's 12 producers to have finished step s-1 ----
    if (s > 0) {
      for (;;) {
        unsigned int v = __hip_atomic_load(fg + pidx, __ATOMIC_RELAXED,
                                           __HIP_MEMORY_SCOPE_AGENT);
        if (__all((int)(v >= (unsigned int)s))) break;
      }
    }

    const f16* hsrc = (s == 0) ? hbuf : (Y + (size_t)(s - 1) * (NB * NH));
    const f16* xsrc = (s == 0) ? xbuf : hsrc;

    half8 Af[NKT];
#pragma unroll
    for (int kt = 0; kt < NKT; ++kt)
      Af[kt] = *(const half8*)(xsrc + arow_off + kt * 32);

    f32x4 acc0 = {0.f,0.f,0.f,0.f}, acc1 = {0.f,0.f,0.f,0.f}, acc2 = {0.f,0.f,0.f,0.f};
    f32x4 acc3 = {0.f,0.f,0.f,0.f}, acc4 = {0.f,0.f,0.f,0.f}, acc5 = {0.f,0.f,0.f,0.f};

#pragma unroll
    for (int kt = 0; kt < NKT; ++kt) {
      acc0 = __builtin_amdgcn_mfma_f32_16x16x32_f16(Af[kt], Bf[0][kt], acc0, 0, 0, 0);
      acc1 = __builtin_amdgcn_mfma_f32_16x16x32_f16(Af[kt], Bf[1][kt], acc1, 0, 0, 0);
      acc2 = __builtin_amdgcn_mfma_f32_16x16x32_f16(Af[kt], Bf[2][kt], acc2, 0, 0, 0);
    }
    if (s == 0) {
#pragma unroll
      for (int kt = 0; kt < NKT; ++kt)
        Af[kt] = *(const half8*)(hbuf + arow_off + kt * 32);
    }
#pragma unroll
    for (int kt = 0; kt < NKT; ++kt) {
      acc3 = __builtin_amdgcn_mfma_f32_16x16x32_f16(Af[kt], Bf[3][kt], acc3, 0, 0, 0);
      acc4 = __builtin_amdgcn_mfma_f32_16x16x32_f16(Af[kt], Bf[4][kt], acc4, 0, 0, 0);
      acc5 = __builtin_amdgcn_mfma_f32_16x16x32_f16(Af[kt], Bf[5][kt], acc5, 0, 0, 0);
    }

    // partials -> LDS   (C/D layout: n = lane&15, m = (lane>>4)*4 + reg)
    const int mrow = (lane >> 4) * 4;
#pragma unroll
    for (int r = 0; r < 4; ++r) {
      int base = (wv * 16 + mrow + r) * PSTRIDE + n15;
      part[base     ] = acc0[r];
      part[base + 16] = acc1[r];
      part[base + 32] = acc2[r];
      part[base + 48] = acc3[r];
      part[base + 64] = acc4[r];
      part[base + 80] = acc5[r];
    }
    __syncthreads();   // A: partials visible

    // gate phase: reduce 4 wave-partials, apply GRU cell
    float gir = bi_r, giz = bi_z, gin = bi_n, ghr = bh_r, ghz = bh_z, ghn = bh_n;
#pragma unroll
    for (int ww = 0; ww < 4; ++ww) {
      const float* p = &part[(ww * 16 + gb) * PSTRIDE + gj];
      gir += p[0];  giz += p[16]; gin += p[32];
      ghr += p[48]; ghz += p[64]; ghn += p[80];
    }
    float rr = 1.f / (1.f + __expf(-(gir + ghr)));
    float zz = 1.f / (1.f + __expf(-(giz + ghz)));
    float xn = gin + rr * ghn;
    float nn = 1.f - 2.f / (__expf(2.f * xn) + 1.f);
    float hnew = (1.f - zz) * nn + zz * hcarry;
    hcarry = hnew;

    // pack pair (gj even|odd) into dword, agent-scope relaxed store -> LLC (sc1)
    unsigned int u = (unsigned int)__builtin_bit_cast(unsigned short, (f16)hnew);
    unsigned int partner = (unsigned int)__shfl_xor((int)u, 1);
    if ((tid & 1) == 0) {
      unsigned int val = u | (partner << 16);
      unsigned int* dst = (unsigned int*)(Y + (size_t)s * (NB * NH) + ywr_off);
      __hip_atomic_store(dst, val, __ATOMIC_RELAXED, __HIP_MEMORY_SCOPE_AGENT);
    }

    // B: each wave drains its vmcnt before s_barrier => after this barrier,
    // every Y store of this WG has reached the coherence point (LLC).
    __syncthreads();
    if (tid == 0)
      __hip_atomic_store(fg + c, (unsigned int)(s + 1), __ATOMIC_RELAXED,
                         __HIP_MEMORY_SCOPE_AGENT);
    // no trailing barrier: next step's poll gates LDS reuse (gate reads done pre-B)
  }
}

__global__ void __launch_bounds__(256)
proj_kernel(const f16* __restrict__ Y, const f16* __restrict__ wlin16,
            const float* __restrict__ b_lin, const int* __restrict__ Tn,
            float* __restrict__ out)
{
  // rows r = s*128 + b over Y viewed as [512*128][768]; each WG does 64 rows x 128 cols
  const int tid = threadIdx.x;
  const int lane = tid & 63;
  const int wv = tid >> 6;
  const int r0 = blockIdx.x * 64 + wv * 16;
  const int n15 = lane & 15;
  const int kg8 = (lane >> 4) * 8;
  const size_t arow_off = (size_t)(r0 + n15) * NH + kg8;

  f32x4 acc[8];
#pragma unroll
  for (int nf = 0; nf < 8; ++nf) acc[nf] = (f32x4){0.f, 0.f, 0.f, 0.f};

  for (int kt = 0; kt < 24; ++kt) {
    half8 a = *(const half8*)(Y + arow_off + kt * 32);
#pragma unroll
    for (int nf = 0; nf < 8; ++nf) {
      half8 bfr = *(const half8*)(wlin16 + (size_t)(nf * 16 + n15) * NH + kt * 32 + kg8);
      acc[nf] = __builtin_amdgcn_mfma_f32_16x16x32_f16(a, bfr, acc[nf], 0, 0, 0);
    }
  }

#pragma unroll
  for (int nf = 0; nf < 8; ++nf) {
    int fcol = nf * 16 + n15;
    float bl = b_lin[fcol];
#pragma unroll
    for (int r = 0; r < 4; ++r) {
      int row = r0 + (lane >> 4) * 4 + r;
      int s = row >> 7, b = row & 127;
      int t = 511 - s;
      float v = (t < Tn[b]) ? (acc[nf][r] + bl) : -1.0f;
      out[((size_t)b * 512 + t) * NFEAT + fcol] = v;
    }
  }
}

extern "C" void kernel_launch(void* const* d_in, const int* in_sizes, int n_in,
                              void* d_out, int out_size, void* d_ws, size_t ws_size,
                              hipStream_t stream) {
  const float* Ho   = (const float*)d_in[0];
  const float* Hn   = (const float*)d_in[1];
  const unsigned int* Traw = (const unsigned int*)d_in[2];
  const float* Wih  = (const float*)d_in[3];
  const float* Whh  = (const float*)d_in[4];
  const float* bih  = (const float*)d_in[5];
  const float* bhh  = (const float*)d_in[6];
  const float* Wlin = (const float*)d_in[7];
  const float* blin = (const float*)d_in[8];
  float* out = (float*)d_out;

  if (ws_size < (size_t)WS_NEED) {
    fill_sentinel<<<1024, 256, 0, stream>>>(out, (long long)out_size);
    return;
  }

  char* ws = (char*)d_ws;
  f16* wih16  = (f16*)(ws + OFF_WIH);
  f16* whh16  = (f16*)(ws + OFF_WHH);
  f16* wlin16 = (f16*)(ws + OFF_WLIN);
  f16* xbuf   = (f16*)(ws + OFF_XBUF);
  f16* hbuf   = (f16*)(ws + OFF_HBUF);
  unsigned int* flg = (unsigned int*)(ws + OFF_FLG);
  f16* Y      = (f16*)(ws + OFF_Y);
  int* Tn     = (int*)(ws + OFF_TN);

  hipMemsetAsync(flg, 0, 16384, stream);
  prep_kernel<<<512, 256, 0, stream>>>(Ho, Hn, Traw, Wih, Whh, Wlin,
                                       wih16, whh16, wlin16, xbuf, hbuf, Tn);
  gru_kernel<<<NWG, 256, 0, stream>>>(wih16, whh16, xbuf, hbuf, Hn, bih, bhh, Y, flg);
  proj_kernel<<<1024, 256, 0, stream>>>(Y, wlin16, blin, Tn, out);
}

// Round 5
// 2084.253 us; speedup vs baseline: 2.0326x; 2.0326x over previous
//
#include <hip/hip_runtime.h>

typedef _Float16 f16;
typedef _Float16 half8 __attribute__((ext_vector_type(8)));
typedef float f32x4 __attribute__((ext_vector_type(4)));

#define SEQ 512
#define NB 128
#define NH 768
#define NFEAT 128
#define NGRP 4
#define BG 32
#define NCOL 48
#define NWG (NGRP*NCOL)
#define KW8 96
#define NKT8 3
#define PSTRIDE 108

// workspace layout
#define OFF_WIH   0LL
#define OFF_WHH   3538944LL
#define OFF_WLIN  7077888LL
#define OFF_XBUF  7274496LL
#define OFF_HBUF  7471104LL
#define OFF_CTR   7667712LL   /* 4 groups * 512 steps * 4B = 8 KB (16 KB reserved) */
#define OFF_Y     7684096LL
#define OFF_TN    108347392LL
#define WS_NEED   (OFF_TN + 1024)

__global__ void fill_sentinel(float* out, long long n) {
  long long i = (long long)blockIdx.x * blockDim.x + threadIdx.x;
  long long stride = (long long)gridDim.x * blockDim.x;
  for (; i < n; i += stride) out[i] = -2.0f;
}

__global__ void prep_kernel(const float* __restrict__ Ho, const float* __restrict__ Hn,
                            const unsigned int* __restrict__ Traw,
                            const float* __restrict__ Wih, const float* __restrict__ Whh,
                            const float* __restrict__ Wlin,
                            f16* __restrict__ wih16, f16* __restrict__ whh16,
                            f16* __restrict__ wlin16,
                            f16* __restrict__ xbuf, f16* __restrict__ hbuf,
                            int* __restrict__ Tn)
{
  long long idx = (long long)blockIdx.x * blockDim.x + threadIdx.x;
  long long stride = (long long)gridDim.x * blockDim.x;
  for (long long i = idx; i < 2304LL * 768LL; i += stride) {
    wih16[i] = (f16)Wih[i];
    whh16[i] = (f16)Whh[i];
  }
  for (long long i = idx; i < 128LL * 768LL; i += stride) {
    long long b = i / 768, h = i % 768;
    wlin16[i] = (f16)Wlin[i];
    xbuf[i] = (f16)Ho[(b * 32 + 31) * 768 + h];   // H_o[:, -1, :]
    hbuf[i] = (f16)Hn[i];                          // H_n[0]
  }
  // Normalize T: detect int64 (all odd 32-bit words zero) vs int32.
  if (blockIdx.x == 0 && threadIdx.x < 128) {
    bool allz = true;
    for (int i = 0; i < 64; ++i) allz = allz && (Traw[2 * i + 1] == 0u);
    int t = threadIdx.x;
    Tn[t] = allz ? (int)Traw[2 * t] : (int)Traw[t];
  }
}

__global__ void __launch_bounds__(512, 1)
gru_kernel(const f16* __restrict__ wih16, const f16* __restrict__ whh16,
           const f16* __restrict__ xbuf, const f16* __restrict__ hbuf,
           const float* __restrict__ Hn,
           const float* __restrict__ b_ih, const float* __restrict__ b_hh,
           f16* __restrict__ Y, unsigned int* __restrict__ ctr)
{
  const int wg  = blockIdx.x;
  const int g   = wg & (NGRP - 1);   // batch group 0..3
  const int c   = wg >> 2;           // column slice 0..47
  const int tid = threadIdx.x;
  const int lane = tid & 63;
  const int wv  = tid >> 6;          // wave 0..7 (K-split)
  const int j0  = c * 16;
  const int ks  = wv * KW8;
  const int bbase = g * BG;

  __shared__ float part[8 * BG * PSTRIDE];   // 110592 B -> 1 WG/CU

  const int n15 = lane & 15;
  const int kg8 = (lane >> 4) * 8;

  // ---- persistent weight fragments: 18 half8 = 72 VGPRs (fits; stays resident) ----
  half8 Bf[6][NKT8];
#pragma unroll
  for (int nt = 0; nt < 6; ++nt) {
    const f16* Wsrc = (nt < 3) ? wih16 : whh16;
    const f16* base = Wsrc + (size_t)((nt % 3) * 768 + j0 + n15) * NH + ks + kg8;
#pragma unroll
    for (int kt = 0; kt < NKT8; ++kt)
      Bf[nt][kt] = *(const half8*)(base + kt * 32);
  }

  // gate-phase assignment: one (batch, col) per thread; h carried in fp32 register
  const int gb = tid >> 4;           // 0..31 batch within group
  const int gj = tid & 15;
  const int jglob = j0 + gj;
  float hcarry = Hn[(size_t)(bbase + gb) * NH + jglob];
  const float bi_r = b_ih[jglob], bi_z = b_ih[768 + jglob], bi_n = b_ih[1536 + jglob];
  const float bh_r = b_hh[jglob], bh_z = b_hh[768 + jglob], bh_n = b_hh[1536 + jglob];

  const size_t arow0 = (size_t)(bbase + n15) * NH + ks + kg8;
  const size_t arow1 = arow0 + (size_t)16 * NH;
  const size_t ywr   = (size_t)(bbase + gb) * NH + jglob;

  unsigned int* cbase = ctr + ((size_t)g << 9);

  for (int s = 0; s < SEQ; ++s) {
    const f16* hsrc = (s == 0) ? hbuf : (Y + (size_t)(s - 1) * (NB * NH));
    const f16* xsrc = (s == 0) ? xbuf : hsrc;

    half8 Af0_0 = *(const half8*)(xsrc + arow0);
    half8 Af0_1 = *(const half8*)(xsrc + arow0 + 32);
    half8 Af0_2 = *(const half8*)(xsrc + arow0 + 64);
    half8 Af1_0 = *(const half8*)(xsrc + arow1);
    half8 Af1_1 = *(const half8*)(xsrc + arow1 + 32);
    half8 Af1_2 = *(const half8*)(xsrc + arow1 + 64);

    f32x4 a00 = {0.f,0.f,0.f,0.f}, a01 = {0.f,0.f,0.f,0.f}, a02 = {0.f,0.f,0.f,0.f};
    f32x4 a03 = {0.f,0.f,0.f,0.f}, a04 = {0.f,0.f,0.f,0.f}, a05 = {0.f,0.f,0.f,0.f};
    f32x4 a10 = {0.f,0.f,0.f,0.f}, a11 = {0.f,0.f,0.f,0.f}, a12 = {0.f,0.f,0.f,0.f};
    f32x4 a13 = {0.f,0.f,0.f,0.f}, a14 = {0.f,0.f,0.f,0.f}, a15 = {0.f,0.f,0.f,0.f};

    // ih gates (use x)
    a00 = __builtin_amdgcn_mfma_f32_16x16x32_f16(Af0_0, Bf[0][0], a00, 0, 0, 0);
    a01 = __builtin_amdgcn_mfma_f32_16x16x32_f16(Af0_0, Bf[1][0], a01, 0, 0, 0);
    a02 = __builtin_amdgcn_mfma_f32_16x16x32_f16(Af0_0, Bf[2][0], a02, 0, 0, 0);
    a10 = __builtin_amdgcn_mfma_f32_16x16x32_f16(Af1_0, Bf[0][0], a10, 0, 0, 0);
    a11 = __builtin_amdgcn_mfma_f32_16x16x32_f16(Af1_0, Bf[1][0], a11, 0, 0, 0);
    a12 = __builtin_amdgcn_mfma_f32_16x16x32_f16(Af1_0, Bf[2][0], a12, 0, 0, 0);
    a00 = __builtin_amdgcn_mfma_f32_16x16x32_f16(Af0_1, Bf[0][1], a00, 0, 0, 0);
    a01 = __builtin_amdgcn_mfma_f32_16x16x32_f16(Af0_1, Bf[1][1], a01, 0, 0, 0);
    a02 = __builtin_amdgcn_mfma_f32_16x16x32_f16(Af0_1, Bf[2][1], a02, 0, 0, 0);
    a10 = __builtin_amdgcn_mfma_f32_16x16x32_f16(Af1_1, Bf[0][1], a10, 0, 0, 0);
    a11 = __builtin_amdgcn_mfma_f32_16x16x32_f16(Af1_1, Bf[1][1], a11, 0, 0, 0);
    a12 = __builtin_amdgcn_mfma_f32_16x16x32_f16(Af1_1, Bf[2][1], a12, 0, 0, 0);
    a00 = __builtin_amdgcn_mfma_f32_16x16x32_f16(Af0_2, Bf[0][2], a00, 0, 0, 0);
    a01 = __builtin_amdgcn_mfma_f32_16x16x32_f16(Af0_2, Bf[1][2], a01, 0, 0, 0);
    a02 = __builtin_amdgcn_mfma_f32_16x16x32_f16(Af0_2, Bf[2][2], a02, 0, 0, 0);
    a10 = __builtin_amdgcn_mfma_f32_16x16x32_f16(Af1_2, Bf[0][2], a10, 0, 0, 0);
    a11 = __builtin_amdgcn_mfma_f32_16x16x32_f16(Af1_2, Bf[1][2], a11, 0, 0, 0);
    a12 = __builtin_amdgcn_mfma_f32_16x16x32_f16(Af1_2, Bf[2][2], a12, 0, 0, 0);

    if (s == 0) {   // hh gates use h0, not x0
      Af0_0 = *(const half8*)(hbuf + arow0);
      Af0_1 = *(const half8*)(hbuf + arow0 + 32);
      Af0_2 = *(const half8*)(hbuf + arow0 + 64);
      Af1_0 = *(const half8*)(hbuf + arow1);
      Af1_1 = *(const half8*)(hbuf + arow1 + 32);
      Af1_2 = *(const half8*)(hbuf + arow1 + 64);
    }

    // hh gates (use h)
    a03 = __builtin_amdgcn_mfma_f32_16x16x32_f16(Af0_0, Bf[3][0], a03, 0, 0, 0);
    a04 = __builtin_amdgcn_mfma_f32_16x16x32_f16(Af0_0, Bf[4][0], a04, 0, 0, 0);
    a05 = __builtin_amdgcn_mfma_f32_16x16x32_f16(Af0_0, Bf[5][0], a05, 0, 0, 0);
    a13 = __builtin_amdgcn_mfma_f32_16x16x32_f16(Af1_0, Bf[3][0], a13, 0, 0, 0);
    a14 = __builtin_amdgcn_mfma_f32_16x16x32_f16(Af1_0, Bf[4][0], a14, 0, 0, 0);
    a15 = __builtin_amdgcn_mfma_f32_16x16x32_f16(Af1_0, Bf[5][0], a15, 0, 0, 0);
    a03 = __builtin_amdgcn_mfma_f32_16x16x32_f16(Af0_1, Bf[3][1], a03, 0, 0, 0);
    a04 = __builtin_amdgcn_mfma_f32_16x16x32_f16(Af0_1, Bf[4][1], a04, 0, 0, 0);
    a05 = __builtin_amdgcn_mfma_f32_16x16x32_f16(Af0_1, Bf[5][1], a05, 0, 0, 0);
    a13 = __builtin_amdgcn_mfma_f32_16x16x32_f16(Af1_1, Bf[3][1], a13, 0, 0, 0);
    a14 = __builtin_amdgcn_mfma_f32_16x16x32_f16(Af1_1, Bf[4][1], a14, 0, 0, 0);
    a15 = __builtin_amdgcn_mfma_f32_16x16x32_f16(Af1_1, Bf[5][1], a15, 0, 0, 0);
    a03 = __builtin_amdgcn_mfma_f32_16x16x32_f16(Af0_2, Bf[3][2], a03, 0, 0, 0);
    a04 = __builtin_amdgcn_mfma_f32_16x16x32_f16(Af0_2, Bf[4][2], a04, 0, 0, 0);
    a05 = __builtin_amdgcn_mfma_f32_16x16x32_f16(Af0_2, Bf[5][2], a05, 0, 0, 0);
    a13 = __builtin_amdgcn_mfma_f32_16x16x32_f16(Af1_2, Bf[3][2], a13, 0, 0, 0);
    a14 = __builtin_amdgcn_mfma_f32_16x16x32_f16(Af1_2, Bf[4][2], a14, 0, 0, 0);
    a15 = __builtin_amdgcn_mfma_f32_16x16x32_f16(Af1_2, Bf[5][2], a15, 0, 0, 0);

    // partials -> LDS   (C/D layout: n = lane&15, m = (lane>>4)*4 + reg)
    const int mrow = (lane >> 4) * 4;
#pragma unroll
    for (int r = 0; r < 4; ++r) {
      int b0 = (wv * BG + mrow + r) * PSTRIDE + n15;        // tile rt=0
      part[b0     ] = a00[r];
      part[b0 + 16] = a01[r];
      part[b0 + 32] = a02[r];
      part[b0 + 48] = a03[r];
      part[b0 + 64] = a04[r];
      part[b0 + 80] = a05[r];
      int b1 = b0 + 16 * PSTRIDE;                            // tile rt=1
      part[b1     ] = a10[r];
      part[b1 + 16] = a11[r];
      part[b1 + 32] = a12[r];
      part[b1 + 48] = a13[r];
      part[b1 + 64] = a14[r];
      part[b1 + 80] = a15[r];
    }
    __syncthreads();   // A: partials visible

    // gate phase: reduce 8 wave-partials, apply GRU cell
    float gir = bi_r, giz = bi_z, gin = bi_n, ghr = bh_r, ghz = bh_z, ghn = bh_n;
#pragma unroll
    for (int ww = 0; ww < 8; ++ww) {
      const float* p = &part[(ww * BG + gb) * PSTRIDE + gj];
      gir += p[0];  giz += p[16]; gin += p[32];
      ghr += p[48]; ghz += p[64]; ghn += p[80];
    }
    float rr = 1.f / (1.f + __expf(-(gir + ghr)));
    float zz = 1.f / (1.f + __expf(-(giz + ghz)));
    float xn = gin + rr * ghn;
    float nn = 1.f - 2.f / (__expf(2.f * xn) + 1.f);
    float hnew = (1.f - zz) * nn + zz * hcarry;
    hcarry = hnew;

    // pack pair (gj even|odd) into dword, agent-scope relaxed store -> LLC (sc1)
    unsigned int u = (unsigned int)__builtin_bit_cast(unsigned short, (f16)hnew);
    unsigned int partner = (unsigned int)__shfl_xor((int)u, 1);
    if ((tid & 1) == 0) {
      unsigned int val = u | (partner << 16);
      unsigned int* dst = (unsigned int*)(Y + (size_t)s * (NB * NH) + ywr);
      __hip_atomic_store(dst, val, __ATOMIC_RELAXED, __HIP_MEMORY_SCOPE_AGENT);
    }

    // B: each wave drains its vmcnt before s_barrier => all Y stores at LLC
    __syncthreads();
    if (tid == 0) {
      unsigned int* cp = cbase + s;
      __hip_atomic_fetch_add(cp, 1u, __ATOMIC_RELAXED, __HIP_MEMORY_SCOPE_AGENT);
      while (__hip_atomic_load(cp, __ATOMIC_RELAXED, __HIP_MEMORY_SCOPE_AGENT) < NCOL)
        __builtin_amdgcn_s_sleep(1);
    }
    __syncthreads();   // C: release
  }
}

__global__ void __launch_bounds__(256)
proj_kernel(const f16* __restrict__ Y, const f16* __restrict__ wlin16,
            const float* __restrict__ b_lin, const int* __restrict__ Tn,
            float* __restrict__ out)
{
  // rows r = s*128 + b over Y viewed as [512*128][768]; each WG does 64 rows x 128 cols
  const int tid = threadIdx.x;
  const int lane = tid & 63;
  const int wv = tid >> 6;
  const int r0 = blockIdx.x * 64 + wv * 16;
  const int n15 = lane & 15;
  const int kg8 = (lane >> 4) * 8;
  const size_t arow_off = (size_t)(r0 + n15) * NH + kg8;

  f32x4 acc[8];
#pragma unroll
  for (int nf = 0; nf < 8; ++nf) acc[nf] = (f32x4){0.f, 0.f, 0.f, 0.f};

  for (int kt = 0; kt < 24; ++kt) {
    half8 a = *(const half8*)(Y + arow_off + kt * 32);
#pragma unroll
    for (int nf = 0; nf < 8; ++nf) {
      half8 bfr = *(const half8*)(wlin16 + (size_t)(nf * 16 + n15) * NH + kt * 32 + kg8);
      acc[nf] = __builtin_amdgcn_mfma_f32_16x16x32_f16(a, bfr, acc[nf], 0, 0, 0);
    }
  }

#pragma unroll
  for (int nf = 0; nf < 8; ++nf) {
    int fcol = nf * 16 + n15;
    float bl = b_lin[fcol];
#pragma unroll
    for (int r = 0; r < 4; ++r) {
      int row = r0 + (lane >> 4) * 4 + r;
      int s = row >> 7, b = row & 127;
      int t = 511 - s;
      float v = (t < Tn[b]) ? (acc[nf][r] + bl) : -1.0f;
      out[((size_t)b * 512 + t) * NFEAT + fcol] = v;
    }
  }
}

extern "C" void kernel_launch(void* const* d_in, const int* in_sizes, int n_in,
                              void* d_out, int out_size, void* d_ws, size_t ws_size,
                              hipStream_t stream) {
  const float* Ho   = (const float*)d_in[0];
  const float* Hn   = (const float*)d_in[1];
  const unsigned int* Traw = (const unsigned int*)d_in[2];
  const float* Wih  = (const float*)d_in[3];
  const float* Whh  = (const float*)d_in[4];
  const float* bih  = (const float*)d_in[5];
  const float* bhh  = (const float*)d_in[6];
  const float* Wlin = (const float*)d_in[7];
  const float* blin = (const float*)d_in[8];
  float* out = (float*)d_out;

  if (ws_size < (size_t)WS_NEED) {
    fill_sentinel<<<1024, 256, 0, stream>>>(out, (long long)out_size);
    return;
  }

  char* ws = (char*)d_ws;
  f16* wih16  = (f16*)(ws + OFF_WIH);
  f16* whh16  = (f16*)(ws + OFF_WHH);
  f16* wlin16 = (f16*)(ws + OFF_WLIN);
  f16* xbuf   = (f16*)(ws + OFF_XBUF);
  f16* hbuf   = (f16*)(ws + OFF_HBUF);
  unsigned int* ctr = (unsigned int*)(ws + OFF_CTR);
  f16* Y      = (f16*)(ws + OFF_Y);
  int* Tn     = (int*)(ws + OFF_TN);

  hipMemsetAsync(ctr, 0, NGRP * SEQ * sizeof(unsigned int), stream);
  prep_kernel<<<512, 256, 0, stream>>>(Ho, Hn, Traw, Wih, Whh, Wlin,
                                       wih16, whh16, wlin16, xbuf, hbuf, Tn);
  gru_kernel<<<NWG, 512, 0, stream>>>(wih16, whh16, xbuf, hbuf, Hn, bih, bhh, Y, ctr);
  proj_kernel<<<1024, 256, 0, stream>>>(Y, wlin16, blin, Tn, out);
}

// Round 6
// 2067.671 us; speedup vs baseline: 2.0489x; 1.0080x over previous
//
#include <hip/hip_runtime.h>

typedef _Float16 f16;
typedef _Float16 half8 __attribute__((ext_vector_type(8)));
typedef float f32x4 __attribute__((ext_vector_type(4)));
typedef int i32x4 __attribute__((ext_vector_type(4)));

#define SEQ 512
#define NB 128
#define NH 768
#define NFEAT 128
#define NGRP 4
#define BG 32
#define NCOL 48
#define NWG (NGRP*NCOL)
#define KW8 96
#define NKT8 3

// workspace layout
#define OFF_WIH   0LL
#define OFF_WHH   3538944LL
#define OFF_WLIN  7077888LL
#define OFF_XBUF  7274496LL
#define OFF_HBUF  7471104LL
#define OFF_CTR   7667712LL   /* 4 groups * 512 steps * 4B = 8 KB (16 KB reserved) */
#define OFF_Y     7684096LL
#define OFF_TN    108347392LL
#define WS_NEED   (OFF_TN + 1024)

__global__ void fill_sentinel(float* out, long long n) {
  long long i = (long long)blockIdx.x * blockDim.x + threadIdx.x;
  long long stride = (long long)gridDim.x * blockDim.x;
  for (; i < n; i += stride) out[i] = -2.0f;
}

__global__ void prep_kernel(const float* __restrict__ Ho, const float* __restrict__ Hn,
                            const unsigned int* __restrict__ Traw,
                            const float* __restrict__ Wih, const float* __restrict__ Whh,
                            const float* __restrict__ Wlin,
                            f16* __restrict__ wih16, f16* __restrict__ whh16,
                            f16* __restrict__ wlin16,
                            f16* __restrict__ xbuf, f16* __restrict__ hbuf,
                            int* __restrict__ Tn)
{
  long long idx = (long long)blockIdx.x * blockDim.x + threadIdx.x;
  long long stride = (long long)gridDim.x * blockDim.x;
  for (long long i = idx; i < 2304LL * 768LL; i += stride) {
    wih16[i] = (f16)Wih[i];
    whh16[i] = (f16)Whh[i];
  }
  for (long long i = idx; i < 128LL * 768LL; i += stride) {
    long long b = i / 768, h = i % 768;
    wlin16[i] = (f16)Wlin[i];
    xbuf[i] = (f16)Ho[(b * 32 + 31) * 768 + h];   // H_o[:, -1, :]
    hbuf[i] = (f16)Hn[i];                          // H_n[0]
  }
  // Normalize T: detect int64 (all odd 32-bit words zero) vs int32.
  if (blockIdx.x == 0 && threadIdx.x < 128) {
    bool allz = true;
    for (int i = 0; i < 64; ++i) allz = allz && (Traw[2 * i + 1] == 0u);
    int t = threadIdx.x;
    Tn[t] = allz ? (int)Traw[2 * t] : (int)Traw[t];
  }
}

__global__ void __launch_bounds__(512, 1)
gru_kernel(const f16* __restrict__ wih16, const f16* __restrict__ whh16,
           const f16* __restrict__ xbuf, const f16* __restrict__ hbuf,
           const float* __restrict__ Hn,
           const float* __restrict__ b_ih, const float* __restrict__ b_hh,
           f16* __restrict__ Y, unsigned int* __restrict__ ctr)
{
  const int wg  = blockIdx.x;
  const int g   = wg & (NGRP - 1);   // batch group 0..3
  const int c   = wg >> 2;           // column slice 0..47
  const int tid = threadIdx.x;
  const int lane = tid & 63;
  const int wv  = tid >> 6;          // wave 0..7 (K-split)
  const int j0  = c * 16;
  const int ks  = wv * KW8;
  const int bbase = g * BG;

  // flat partial buffer: [wv][tile(12)][lane] of f32x4  (98304 B -> 1 WG/CU)
  __shared__ float pbuf[8 * 12 * 64 * 4];

  const int n15 = lane & 15;
  const int kg8 = (lane >> 4) * 8;

  // ---- persistent weight fragments. VOLATILE loads: cannot be rematerialized,
  // so the 18 half8 (72 VGPRs) stay live across the step loop. ----
  half8 Bf[6][NKT8];
#pragma unroll
  for (int nt = 0; nt < 6; ++nt) {
    const f16* Wsrc = (nt < 3) ? wih16 : whh16;
    const f16* base = Wsrc + (size_t)((nt % 3) * 768 + j0 + n15) * NH + ks + kg8;
#pragma unroll
    for (int kt = 0; kt < NKT8; ++kt) {
      i32x4 raw = *(const volatile i32x4*)(base + kt * 32);
      Bf[nt][kt] = __builtin_bit_cast(half8, raw);
    }
  }

  // gate-phase assignment: one (batch, col) per thread; h carried in fp32 register
  const int gb = tid >> 4;           // 0..31 batch within group
  const int gj = tid & 15;
  const int jglob = j0 + gj;
  float hcarry = Hn[(size_t)(bbase + gb) * NH + jglob];
  const float bi_r = b_ih[jglob], bi_z = b_ih[768 + jglob], bi_n = b_ih[1536 + jglob];
  const float bh_r = b_hh[jglob], bh_z = b_hh[768 + jglob], bh_n = b_hh[1536 + jglob];

  const size_t arow0 = (size_t)(bbase + n15) * NH + ks + kg8;
  const size_t arow1 = arow0 + (size_t)16 * NH;
  const size_t ywr   = (size_t)(bbase + gb) * NH + jglob;

  // gate-phase read offset: value (batch m=gb, col n=gj) of tile rt=gb>>4, gate nt
  // sits at float index  wv*3072 + (rt*6+nt)*256 + ((mt>>2)*16+gj)*4 + (mt&3)
  const int rt_g = gb >> 4, mt = gb & 15;
  const int off0 = rt_g * 1536 + (((mt >> 2) * 16 + gj) << 2) + (mt & 3);

  unsigned int* cbase = ctr + ((size_t)g << 9);

  for (int s = 0; s < SEQ; ++s) {
    const f16* hsrc = (s == 0) ? hbuf : (Y + (size_t)(s - 1) * (NB * NH));
    const f16* xsrc = (s == 0) ? xbuf : hsrc;

    half8 Af0_0 = *(const half8*)(xsrc + arow0);
    half8 Af0_1 = *(const half8*)(xsrc + arow0 + 32);
    half8 Af0_2 = *(const half8*)(xsrc + arow0 + 64);
    half8 Af1_0 = *(const half8*)(xsrc + arow1);
    half8 Af1_1 = *(const half8*)(xsrc + arow1 + 32);
    half8 Af1_2 = *(const half8*)(xsrc + arow1 + 64);

    f32x4 a00 = {0.f,0.f,0.f,0.f}, a01 = {0.f,0.f,0.f,0.f}, a02 = {0.f,0.f,0.f,0.f};
    f32x4 a03 = {0.f,0.f,0.f,0.f}, a04 = {0.f,0.f,0.f,0.f}, a05 = {0.f,0.f,0.f,0.f};
    f32x4 a10 = {0.f,0.f,0.f,0.f}, a11 = {0.f,0.f,0.f,0.f}, a12 = {0.f,0.f,0.f,0.f};
    f32x4 a13 = {0.f,0.f,0.f,0.f}, a14 = {0.f,0.f,0.f,0.f}, a15 = {0.f,0.f,0.f,0.f};

    // ih gates (use x)
    a00 = __builtin_amdgcn_mfma_f32_16x16x32_f16(Af0_0, Bf[0][0], a00, 0, 0, 0);
    a01 = __builtin_amdgcn_mfma_f32_16x16x32_f16(Af0_0, Bf[1][0], a01, 0, 0, 0);
    a02 = __builtin_amdgcn_mfma_f32_16x16x32_f16(Af0_0, Bf[2][0], a02, 0, 0, 0);
    a10 = __builtin_amdgcn_mfma_f32_16x16x32_f16(Af1_0, Bf[0][0], a10, 0, 0, 0);
    a11 = __builtin_amdgcn_mfma_f32_16x16x32_f16(Af1_0, Bf[1][0], a11, 0, 0, 0);
    a12 = __builtin_amdgcn_mfma_f32_16x16x32_f16(Af1_0, Bf[2][0], a12, 0, 0, 0);
    a00 = __builtin_amdgcn_mfma_f32_16x16x32_f16(Af0_1, Bf[0][1], a00, 0, 0, 0);
    a01 = __builtin_amdgcn_mfma_f32_16x16x32_f16(Af0_1, Bf[1][1], a01, 0, 0, 0);
    a02 = __builtin_amdgcn_mfma_f32_16x16x32_f16(Af0_1, Bf[2][1], a02, 0, 0, 0);
    a10 = __builtin_amdgcn_mfma_f32_16x16x32_f16(Af1_1, Bf[0][1], a10, 0, 0, 0);
    a11 = __builtin_amdgcn_mfma_f32_16x16x32_f16(Af1_1, Bf[1][1], a11, 0, 0, 0);
    a12 = __builtin_amdgcn_mfma_f32_16x16x32_f16(Af1_1, Bf[2][1], a12, 0, 0, 0);
    a00 = __builtin_amdgcn_mfma_f32_16x16x32_f16(Af0_2, Bf[0][2], a00, 0, 0, 0);
    a01 = __builtin_amdgcn_mfma_f32_16x16x32_f16(Af0_2, Bf[1][2], a01, 0, 0, 0);
    a02 = __builtin_amdgcn_mfma_f32_16x16x32_f16(Af0_2, Bf[2][2], a02, 0, 0, 0);
    a10 = __builtin_amdgcn_mfma_f32_16x16x32_f16(Af1_2, Bf[0][2], a10, 0, 0, 0);
    a11 = __builtin_amdgcn_mfma_f32_16x16x32_f16(Af1_2, Bf[1][2], a11, 0, 0, 0);
    a12 = __builtin_amdgcn_mfma_f32_16x16x32_f16(Af1_2, Bf[2][2], a12, 0, 0, 0);

    if (s == 0) {   // hh gates use h0, not x0
      Af0_0 = *(const half8*)(hbuf + arow0);
      Af0_1 = *(const half8*)(hbuf + arow0 + 32);
      Af0_2 = *(const half8*)(hbuf + arow0 + 64);
      Af1_0 = *(const half8*)(hbuf + arow1);
      Af1_1 = *(const half8*)(hbuf + arow1 + 32);
      Af1_2 = *(const half8*)(hbuf + arow1 + 64);
    }

    // hh gates (use h)
    a03 = __builtin_amdgcn_mfma_f32_16x16x32_f16(Af0_0, Bf[3][0], a03, 0, 0, 0);
    a04 = __builtin_amdgcn_mfma_f32_16x16x32_f16(Af0_0, Bf[4][0], a04, 0, 0, 0);
    a05 = __builtin_amdgcn_mfma_f32_16x16x32_f16(Af0_0, Bf[5][0], a05, 0, 0, 0);
    a13 = __builtin_amdgcn_mfma_f32_16x16x32_f16(Af1_0, Bf[3][0], a13, 0, 0, 0);
    a14 = __builtin_amdgcn_mfma_f32_16x16x32_f16(Af1_0, Bf[4][0], a14, 0, 0, 0);
    a15 = __builtin_amdgcn_mfma_f32_16x16x32_f16(Af1_0, Bf[5][0], a15, 0, 0, 0);
    a03 = __builtin_amdgcn_mfma_f32_16x16x32_f16(Af0_1, Bf[3][1], a03, 0, 0, 0);
    a04 = __builtin_amdgcn_mfma_f32_16x16x32_f16(Af0_1, Bf[4][1], a04, 0, 0, 0);
    a05 = __builtin_amdgcn_mfma_f32_16x16x32_f16(Af0_1, Bf[5][1], a05, 0, 0, 0);
    a13 = __builtin_amdgcn_mfma_f32_16x16x32_f16(Af1_1, Bf[3][1], a13, 0, 0, 0);
    a14 = __builtin_amdgcn_mfma_f32_16x16x32_f16(Af1_1, Bf[4][1], a14, 0, 0, 0);
    a15 = __builtin_amdgcn_mfma_f32_16x16x32_f16(Af1_1, Bf[5][1], a15, 0, 0, 0);
    a03 = __builtin_amdgcn_mfma_f32_16x16x32_f16(Af0_2, Bf[3][2], a03, 0, 0, 0);
    a04 = __builtin_amdgcn_mfma_f32_16x16x32_f16(Af0_2, Bf[4][2], a04, 0, 0, 0);
    a05 = __builtin_amdgcn_mfma_f32_16x16x32_f16(Af0_2, Bf[5][2], a05, 0, 0, 0);
    a13 = __builtin_amdgcn_mfma_f32_16x16x32_f16(Af1_2, Bf[3][2], a13, 0, 0, 0);
    a14 = __builtin_amdgcn_mfma_f32_16x16x32_f16(Af1_2, Bf[4][2], a14, 0, 0, 0);
    a15 = __builtin_amdgcn_mfma_f32_16x16x32_f16(Af1_2, Bf[5][2], a15, 0, 0, 0);

    // partials -> LDS, vectorized: 12 x ds_write_b128 per thread (contiguous per tile)
    {
      f32x4* pb = (f32x4*)pbuf;
      const int wbase = wv * 768 + lane;      // f32x4 units
      pb[wbase +   0] = a00;  pb[wbase +  64] = a01;  pb[wbase + 128] = a02;
      pb[wbase + 192] = a03;  pb[wbase + 256] = a04;  pb[wbase + 320] = a05;
      pb[wbase + 384] = a10;  pb[wbase + 448] = a11;  pb[wbase + 512] = a12;
      pb[wbase + 576] = a13;  pb[wbase + 640] = a14;  pb[wbase + 704] = a15;
    }
    __syncthreads();   // A: partials visible

    // gate phase: reduce 8 wave-partials, apply GRU cell
    float gir = bi_r, giz = bi_z, gin = bi_n, ghr = bh_r, ghz = bh_z, ghn = bh_n;
#pragma unroll
    for (int ww = 0; ww < 8; ++ww) {
      const float* p = pbuf + ww * 3072 + off0;
      gir += p[0];    giz += p[256];  gin += p[512];
      ghr += p[768];  ghz += p[1024]; ghn += p[1280];
    }
    float rr = 1.f / (1.f + __expf(-(gir + ghr)));
    float zz = 1.f / (1.f + __expf(-(giz + ghz)));
    float xn = gin + rr * ghn;
    float nn = 1.f - 2.f / (__expf(2.f * xn) + 1.f);
    float hnew = (1.f - zz) * nn + zz * hcarry;
    hcarry = hnew;

    // pack pair (gj even|odd) into dword, agent-scope relaxed store -> LLC (sc1)
    unsigned int u = (unsigned int)__builtin_bit_cast(unsigned short, (f16)hnew);
    unsigned int partner = (unsigned int)__shfl_xor((int)u, 1);
    if ((tid & 1) == 0) {
      unsigned int val = u | (partner << 16);
      unsigned int* dst = (unsigned int*)(Y + (size_t)s * (NB * NH) + ywr);
      __hip_atomic_store(dst, val, __ATOMIC_RELAXED, __HIP_MEMORY_SCOPE_AGENT);
    }

    // B: each wave drains its vmcnt before s_barrier => all Y stores at LLC
    __syncthreads();
    if (tid == 0) {
      unsigned int* cp = cbase + s;
      __hip_atomic_fetch_add(cp, 1u, __ATOMIC_RELAXED, __HIP_MEMORY_SCOPE_AGENT);
      while (__hip_atomic_load(cp, __ATOMIC_RELAXED, __HIP_MEMORY_SCOPE_AGENT) < NCOL)
        __builtin_amdgcn_s_sleep(1);
    }
    __syncthreads();   // C: release
  }
}

__global__ void __launch_bounds__(256)
proj_kernel(const f16* __restrict__ Y, const f16* __restrict__ wlin16,
            const float* __restrict__ b_lin, const int* __restrict__ Tn,
            float* __restrict__ out)
{
  // rows r = s*128 + b over Y viewed as [512*128][768]; each WG does 64 rows x 128 cols
  const int tid = threadIdx.x;
  const int lane = tid & 63;
  const int wv = tid >> 6;
  const int r0 = blockIdx.x * 64 + wv * 16;
  const int n15 = lane & 15;
  const int kg8 = (lane >> 4) * 8;
  const size_t arow_off = (size_t)(r0 + n15) * NH + kg8;

  f32x4 acc[8];
#pragma unroll
  for (int nf = 0; nf < 8; ++nf) acc[nf] = (f32x4){0.f, 0.f, 0.f, 0.f};

  for (int kt = 0; kt < 24; ++kt) {
    half8 a = *(const half8*)(Y + arow_off + kt * 32);
#pragma unroll
    for (int nf = 0; nf < 8; ++nf) {
      half8 bfr = *(const half8*)(wlin16 + (size_t)(nf * 16 + n15) * NH + kt * 32 + kg8);
      acc[nf] = __builtin_amdgcn_mfma_f32_16x16x32_f16(a, bfr, acc[nf], 0, 0, 0);
    }
  }

#pragma unroll
  for (int nf = 0; nf < 8; ++nf) {
    int fcol = nf * 16 + n15;
    float bl = b_lin[fcol];
#pragma unroll
    for (int r = 0; r < 4; ++r) {
      int row = r0 + (lane >> 4) * 4 + r;
      int s = row >> 7, b = row & 127;
      int t = 511 - s;
      float v = (t < Tn[b]) ? (acc[nf][r] + bl) : -1.0f;
      out[((size_t)b * 512 + t) * NFEAT + fcol] = v;
    }
  }
}

extern "C" void kernel_launch(void* const* d_in, const int* in_sizes, int n_in,
                              void* d_out, int out_size, void* d_ws, size_t ws_size,
                              hipStream_t stream) {
  const float* Ho   = (const float*)d_in[0];
  const float* Hn   = (const float*)d_in[1];
  const unsigned int* Traw = (const unsigned int*)d_in[2];
  const float* Wih  = (const float*)d_in[3];
  const float* Whh  = (const float*)d_in[4];
  const float* bih  = (const float*)d_in[5];
  const float* bhh  = (const float*)d_in[6];
  const float* Wlin = (const float*)d_in[7];
  const float* blin = (const float*)d_in[8];
  float* out = (float*)d_out;

  if (ws_size < (size_t)WS_NEED) {
    fill_sentinel<<<1024, 256, 0, stream>>>(out, (long long)out_size);
    return;
  }

  char* ws = (char*)d_ws;
  f16* wih16  = (f16*)(ws + OFF_WIH);
  f16* whh16  = (f16*)(ws + OFF_WHH);
  f16* wlin16 = (f16*)(ws + OFF_WLIN);
  f16* xbuf   = (f16*)(ws + OFF_XBUF);
  f16* hbuf   = (f16*)(ws + OFF_HBUF);
  unsigned int* ctr = (unsigned int*)(ws + OFF_CTR);
  f16* Y      = (f16*)(ws + OFF_Y);
  int* Tn     = (int*)(ws + OFF_TN);

  hipMemsetAsync(ctr, 0, NGRP * SEQ * sizeof(unsigned int), stream);
  prep_kernel<<<512, 256, 0, stream>>>(Ho, Hn, Traw, Wih, Whh, Wlin,
                                       wih16, whh16, wlin16, xbuf, hbuf, Tn);
  gru_kernel<<<NWG, 512, 0, stream>>>(wih16, whh16, xbuf, hbuf, Hn, bih, bhh, Y, ctr);
  proj_kernel<<<1024, 256, 0, stream>>>(Y, wlin16, blin, Tn, out);
}